// Round 1
// baseline (94.587 us; speedup 1.0000x reference)
//
#include <hip/hip_runtime.h>

#define T_TOK 32768
#define E_EXP 256
#define K_SEL 8
#define D_DEV 8
#define SLOTS (E_EXP / D_DEV)   // 32 experts per device

// ---------------------------------------------------------------------------
// Setup: dev_of_expert[e] = argmax_d mapping[e][d];  pos[e] = stable-sort rank
// (perm = argsort(dev_of_expert, stable); pos = inverse perm).
// One block, 256 threads. Reruns every launch (ws is re-poisoned).
// ---------------------------------------------------------------------------
__global__ void moe_setup_kernel(const int* __restrict__ mapping,
                                 int* __restrict__ dev_out,
                                 int* __restrict__ pos_out) {
    __shared__ int sdev[E_EXP];
    int e = threadIdx.x;
    int best = mapping[e * D_DEV];
    int dev = 0;
#pragma unroll
    for (int d = 1; d < D_DEV; ++d) {
        int v = mapping[e * D_DEV + d];
        if (v > best) { best = v; dev = d; }
    }
    sdev[e] = dev;
    __syncthreads();
    int p = 0;
    for (int e2 = 0; e2 < E_EXP; ++e2) {
        int d2 = sdev[e2];
        p += (d2 < dev) || (d2 == dev && e2 < e);
    }
    dev_out[e] = dev;
    pos_out[e] = p;
}

// ---------------------------------------------------------------------------
// Main: one wave per token (64 lanes x 4 experts), 4 tokens per block.
// ---------------------------------------------------------------------------
__global__ __launch_bounds__(256) void moe_remap_kernel(
    const float* __restrict__ topk, const int* __restrict__ meta,
    const int* __restrict__ dev_of_expert, const int* __restrict__ pos,
    float* __restrict__ out_remap, float* __restrict__ out_mask) {
    __shared__ unsigned int sdm[4];

    const int tid  = threadIdx.x;
    const int wave = tid >> 6;
    const int lane = tid & 63;
    const int t    = blockIdx.x * 4 + wave;

    // meta[t][0..7] — wave-uniform address, HW broadcasts
    const int4* mp = (const int4*)(meta + (size_t)t * K_SEL);
    int4 m01 = mp[0];
    int4 m23 = mp[1];
    int mv[8] = {m01.x, m01.y, m01.z, m01.w, m23.x, m23.y, m23.z, m23.w};

    // selection bits for this lane's 4 experts [lane*4, lane*4+4)
    unsigned sel = 0;
#pragma unroll
    for (int k = 0; k < K_SEL; ++k) {
        sel |= ((mv[k] >> 2) == lane) ? (1u << (mv[k] & 3)) : 0u;
    }

    // lane 0: per-token device mask (8 L1-cached lookups)
    if (lane == 0) {
        unsigned dm = 0;
#pragma unroll
        for (int k = 0; k < K_SEL; ++k) dm |= 1u << dev_of_expert[mv[k]];
        sdm[wave] = dm;
    }

    // gated scores for 4 experts
    float4 v = *(const float4*)(topk + (size_t)t * E_EXP + lane * 4);
    v.x = (sel & 1u) ? v.x : 0.0f;
    v.y = (sel & 2u) ? v.y : 0.0f;
    v.z = (sel & 4u) ? v.z : 0.0f;
    v.w = (sel & 8u) ? v.w : 0.0f;

    // remap: expert e at position p -> out[(p/32)*T*32 + t*32 + (p%32)]
    int4 p4 = *(const int4*)(pos + lane * 4);
    if (p4.y == p4.x + 1 && p4.z == p4.x + 2 && p4.w == p4.x + 3 &&
        (p4.x & 3) == 0) {
        // contiguous positions (true for the block-contiguous mapping): float4
        const int d = p4.x >> 5, j = p4.x & 31;
        *(float4*)(out_remap + (size_t)d * T_TOK * SLOTS + (size_t)t * SLOTS + j) = v;
    } else {
        float vv[4] = {v.x, v.y, v.z, v.w};
        int   pp[4] = {p4.x, p4.y, p4.z, p4.w};
#pragma unroll
        for (int i = 0; i < 4; ++i) {
            out_remap[(size_t)(pp[i] >> 5) * T_TOK * SLOTS + (size_t)t * SLOTS +
                      (pp[i] & 31)] = vv[i];
        }
    }

    __syncthreads();
    // reduced mask: OR over token pairs; block holds tokens 4b..4b+3 -> 2 rows
    if (tid < 16) {
        const int pair = tid >> 3, d = tid & 7;
        const unsigned dm = sdm[pair * 2] | sdm[pair * 2 + 1];
        const int row = (blockIdx.x * 4) / 2 + pair;
        out_mask[(size_t)row * D_DEV + d] = ((dm >> d) & 1u) ? 1.0f : 0.0f;
    }
}

extern "C" void kernel_launch(void* const* d_in, const int* in_sizes, int n_in,
                              void* d_out, int out_size, void* d_ws, size_t ws_size,
                              hipStream_t stream) {
    const float* topk    = (const float*)d_in[0];
    const int*   mapping = (const int*)d_in[1];
    const int*   meta    = (const int*)d_in[2];

    float* out_remap = (float*)d_out;
    float* out_mask  = out_remap + (size_t)D_DEV * T_TOK * SLOTS;  // 8,388,608

    int* dev_ws = (int*)d_ws;
    int* pos_ws = dev_ws + E_EXP;  // keeps 16B alignment for int4 loads

    moe_setup_kernel<<<1, 256, 0, stream>>>(mapping, dev_ws, pos_ws);
    moe_remap_kernel<<<T_TOK / 4, 256, 0, stream>>>(topk, meta, dev_ws, pos_ws,
                                                    out_remap, out_mask);
}